// Round 5
// baseline (792.158 us; speedup 1.0000x reference)
//
#include <hip/hip_runtime.h>
#include <stdint.h>

// GCN: out = D^-1 A (relu(D^-1 A (feat W1) + b1) W2) + b2
//
// Pipeline (path A, zero global data atomics, src-sorted records):
//   k_transform1 : z1 = feat @ W1                                  [N,2]
//   k_build      : bucket edges by dst into fixed-CAP regions (LDS hist +
//                  one global reservation atomic per (block,bucket)).
//                  rec = (dst_local<<20) | src
//   k_sort       : per dst-bucket counting sort of records by src-bucket
//                  (512 bins of 2048 nodes) -> recs2.  Gather locality.
//   k_agg1       : per bucket: LDS-accumulate (z1[src] float2, deg),
//                  epilogue h = relu(agg/deg + b1)                 [N,2]
//   k_agg2       : per bucket: LDS-accumulate h[src] (float2),
//                  epilogue out = (agg/deg) @ W2 + b2              [N,3]
//
// ws words: recs[NBUCK*CAP] | recs2[NBUCK*CAP] | gcnt[NBUCK] | deg[N] |
//           z1[2N] | h[2N]

#define BUCKBITS 9
#define NBUCK (1 << BUCKBITS)      // 512 dst buckets
#define LOCBITS 11
#define LOCN (1 << LOCBITS)        // 2048 nodes / bucket
#define SRCBITS 20
#define SRCMASK ((1u << SRCBITS) - 1u)
#define NSB 512                    // src buckets (src >> LOCBITS)
#define CAP 35072                  // mean 32768 + 12.7 sigma (uniform dst)
#define BBLK 512
#define BGRID 512
#define ABLK 512

__global__ void k_transform1(const float* __restrict__ feat,
                             const float* __restrict__ W1,
                             float* __restrict__ z1, int N) {
    int i = blockIdx.x * blockDim.x + threadIdx.x;
    if (i >= N) return;
    float f0 = feat[3 * i + 0];
    float f1 = feat[3 * i + 1];
    float f2 = feat[3 * i + 2];
    float2 z;
    z.x = f0 * W1[0] + f1 * W1[2] + f2 * W1[4];
    z.y = f0 * W1[1] + f1 * W1[3] + f2 * W1[5];
    reinterpret_cast<float2*>(z1)[i] = z;
}

__global__ __launch_bounds__(BBLK) void k_build(const int* __restrict__ src,
                                                const int* __restrict__ dst,
                                                uint32_t* __restrict__ gcnt,
                                                uint32_t* __restrict__ recs, int E) {
    __shared__ uint32_t hist[NBUCK];
    __shared__ uint32_t cur[NBUCK];
    int blk = blockIdx.x;
    for (int i = threadIdx.x; i < NBUCK; i += blockDim.x) hist[i] = 0u;
    __syncthreads();

    int chunk = (((E + (int)gridDim.x - 1) / (int)gridDim.x) + 3) & ~3;
    int beg = blk * chunk;
    int end = min(E, beg + chunk);
    int cnt = end - beg;
    if (cnt < 0) cnt = 0;
    int n4 = cnt >> 2;

    const int4* d4 = reinterpret_cast<const int4*>(dst + beg);
    for (int j = threadIdx.x; j < n4; j += blockDim.x) {
        int4 d = d4[j];
        atomicAdd(&hist[((unsigned)d.x) >> LOCBITS], 1u);
        atomicAdd(&hist[((unsigned)d.y) >> LOCBITS], 1u);
        atomicAdd(&hist[((unsigned)d.z) >> LOCBITS], 1u);
        atomicAdd(&hist[((unsigned)d.w) >> LOCBITS], 1u);
    }
    for (int e = beg + (n4 << 2) + threadIdx.x; e < end; e += blockDim.x)
        atomicAdd(&hist[((unsigned)dst[e]) >> LOCBITS], 1u);
    __syncthreads();

    for (int b = threadIdx.x; b < NBUCK; b += blockDim.x)
        cur[b] = atomicAdd(&gcnt[b], hist[b]);
    __syncthreads();

    const int4* s4 = reinterpret_cast<const int4*>(src + beg);
    for (int j = threadIdx.x; j < n4; j += blockDim.x) {
        int4 d = d4[j];
        int4 s = s4[j];
        int dd[4] = {d.x, d.y, d.z, d.w};
        int ss[4] = {s.x, s.y, s.z, s.w};
#pragma unroll
        for (int q = 0; q < 4; ++q) {
            unsigned dv = (unsigned)dd[q];
            unsigned b = dv >> LOCBITS;
            unsigned loc = dv & (LOCN - 1u);
            unsigned pos = atomicAdd(&cur[b], 1u);
            recs[(size_t)b * CAP + pos] = (loc << SRCBITS) | (unsigned)ss[q];
        }
    }
    for (int e = beg + (n4 << 2) + threadIdx.x; e < end; e += blockDim.x) {
        unsigned dv = (unsigned)dst[e];
        unsigned b = dv >> LOCBITS;
        unsigned loc = dv & (LOCN - 1u);
        unsigned pos = atomicAdd(&cur[b], 1u);
        recs[(size_t)b * CAP + pos] = (loc << SRCBITS) | (unsigned)src[e];
    }
}

// per dst-bucket: counting sort of records by src-bucket (src >> LOCBITS)
__global__ __launch_bounds__(ABLK) void k_sort(const uint32_t* __restrict__ recs,
                                               const uint32_t* __restrict__ gcnt,
                                               uint32_t* __restrict__ recs2) {
    __shared__ uint32_t hist[NSB];
    __shared__ uint32_t x[NSB], y[NSB];
    __shared__ uint32_t cur[NSB];
    int b = blockIdx.x;
    for (int i = threadIdx.x; i < NSB; i += blockDim.x) hist[i] = 0u;
    __syncthreads();
    uint32_t cnt = gcnt[b];
    const uint32_t* r = recs + (size_t)b * CAP;
    for (uint32_t i = threadIdx.x; i < cnt; i += blockDim.x)
        atomicAdd(&hist[(r[i] & SRCMASK) >> LOCBITS], 1u);
    __syncthreads();
    for (int i = threadIdx.x; i < NSB; i += blockDim.x) x[i] = hist[i];
    __syncthreads();
    uint32_t* in = x; uint32_t* out = y;
    for (int off = 1; off < NSB; off <<= 1) {
        for (int i = threadIdx.x; i < NSB; i += blockDim.x)
            out[i] = in[i] + (i >= off ? in[i - off] : 0u);
        __syncthreads();
        uint32_t* t = in; in = out; out = t;
    }
    for (int i = threadIdx.x; i < NSB; i += blockDim.x)
        cur[i] = (i > 0) ? in[i - 1] : 0u;   // exclusive
    __syncthreads();
    uint32_t* w = recs2 + (size_t)b * CAP;
    for (uint32_t i = threadIdx.x; i < cnt; i += blockDim.x) {
        uint32_t rec = r[i];
        uint32_t sb = (rec & SRCMASK) >> LOCBITS;
        uint32_t pos = atomicAdd(&cur[sb], 1u);
        w[pos] = rec;
    }
}

// layer-1 aggregation: gather z1[src] (float2) + deg; epilogue h = relu(.)
__global__ __launch_bounds__(ABLK) void k_agg1(const uint32_t* __restrict__ recs,
                                               const uint32_t* __restrict__ gcnt,
                                               const float* __restrict__ z1,
                                               const float* __restrict__ b1,
                                               float* __restrict__ deg,
                                               float* __restrict__ h, int N) {
    __shared__ float a0[LOCN], a1[LOCN], dg[LOCN];
    int b = blockIdx.x;
    for (int i = threadIdx.x; i < LOCN; i += blockDim.x) {
        a0[i] = 0.0f; a1[i] = 0.0f; dg[i] = 0.0f;
    }
    __syncthreads();
    uint32_t cnt = gcnt[b];
    const uint32_t* r = recs + (size_t)b * CAP;
    const float2* z = reinterpret_cast<const float2*>(z1);
    for (uint32_t i = threadIdx.x; i < cnt; i += blockDim.x) {
        uint32_t rec = r[i];
        uint32_t s = rec & SRCMASK;
        uint32_t loc = rec >> SRCBITS;
        float2 v = z[s];
        atomicAdd(&a0[loc], v.x);
        atomicAdd(&a1[loc], v.y);
        atomicAdd(&dg[loc], 1.0f);
    }
    __syncthreads();
    float b10 = b1[0], b11 = b1[1];
    int base = b << LOCBITS;
    for (int i = threadIdx.x; i < LOCN; i += blockDim.x) {
        int n = base + i;
        if (n >= N) break;
        float d = dg[i];
        deg[n] = d;
        float di = d > 0.0f ? 1.0f / d : 0.0f;
        float2 hv;
        hv.x = fmaxf(a0[i] * di + b10, 0.0f);
        hv.y = fmaxf(a1[i] * di + b11, 0.0f);
        reinterpret_cast<float2*>(h)[n] = hv;
    }
}

// layer-2 aggregation: gather h[src] (float2); epilogue out = (agg/deg)@W2 + b2
__global__ __launch_bounds__(ABLK) void k_agg2(const uint32_t* __restrict__ recs,
                                               const uint32_t* __restrict__ gcnt,
                                               const float* __restrict__ h,
                                               const float* __restrict__ W2,
                                               const float* __restrict__ b2,
                                               const float* __restrict__ deg,
                                               float* __restrict__ out, int N) {
    __shared__ float a0[LOCN], a1[LOCN];
    int b = blockIdx.x;
    for (int i = threadIdx.x; i < LOCN; i += blockDim.x) {
        a0[i] = 0.0f; a1[i] = 0.0f;
    }
    __syncthreads();
    uint32_t cnt = gcnt[b];
    const uint32_t* r = recs + (size_t)b * CAP;
    const float2* z = reinterpret_cast<const float2*>(h);
    for (uint32_t i = threadIdx.x; i < cnt; i += blockDim.x) {
        uint32_t rec = r[i];
        uint32_t s = rec & SRCMASK;
        uint32_t loc = rec >> SRCBITS;
        float2 v = z[s];
        atomicAdd(&a0[loc], v.x);
        atomicAdd(&a1[loc], v.y);
    }
    __syncthreads();
    float w0 = W2[0], w1 = W2[1], w2 = W2[2], w3 = W2[3], w4 = W2[4], w5 = W2[5];
    float b20 = b2[0], b21 = b2[1], b22 = b2[2];
    int base = b << LOCBITS;
    for (int i = threadIdx.x; i < LOCN; i += blockDim.x) {
        int n = base + i;
        if (n >= N) break;
        float d = deg[n];
        float di = d > 0.0f ? 1.0f / d : 0.0f;
        float h0 = a0[i] * di;
        float h1 = a1[i] * di;
        out[3 * n + 0] = h0 * w0 + h1 * w3 + b20;
        out[3 * n + 1] = h0 * w1 + h1 * w4 + b21;
        out[3 * n + 2] = h0 * w2 + h1 * w5 + b22;
    }
}

// ---------- fallback path (proven, global atomics) ----------
__global__ void k_edge1(const int* __restrict__ src, const int* __restrict__ dst,
                        const float* __restrict__ z1,
                        float* __restrict__ agg1, float* __restrict__ deg, int E) {
    int t = blockIdx.x * blockDim.x + threadIdx.x;
    int stride = gridDim.x * blockDim.x;
    const float2* z = reinterpret_cast<const float2*>(z1);
    for (int e = t; e < E; e += stride) {
        int s = src[e], d = dst[e];
        float2 v = z[s];
        atomicAdd(&agg1[2 * d + 0], v.x);
        atomicAdd(&agg1[2 * d + 1], v.y);
        atomicAdd(&deg[d], 1.0f);
    }
}
__global__ void k_mid(const float* __restrict__ agg1, const float* __restrict__ deg,
                      const float* __restrict__ b1, const float* __restrict__ W2,
                      float* __restrict__ z2, int N) {
    int i = blockIdx.x * blockDim.x + threadIdx.x;
    if (i >= N) return;
    float dgv = deg[i];
    float di = dgv > 0.0f ? 1.0f / dgv : 0.0f;
    float2 a = reinterpret_cast<const float2*>(agg1)[i];
    float h0 = fmaxf(a.x * di + b1[0], 0.0f);
    float h1 = fmaxf(a.y * di + b1[1], 0.0f);
    z2[3 * i + 0] = h0 * W2[0] + h1 * W2[3];
    z2[3 * i + 1] = h0 * W2[1] + h1 * W2[4];
    z2[3 * i + 2] = h0 * W2[2] + h1 * W2[5];
}
__global__ void k_edge2(const int* __restrict__ src, const int* __restrict__ dst,
                        const float* __restrict__ z2, float* __restrict__ agg2, int E) {
    int t = blockIdx.x * blockDim.x + threadIdx.x;
    int stride = gridDim.x * blockDim.x;
    for (int e = t; e < E; e += stride) {
        int sv = src[e], dv = dst[e];
        atomicAdd(&agg2[3 * dv + 0], z2[3 * sv + 0]);
        atomicAdd(&agg2[3 * dv + 1], z2[3 * sv + 1]);
        atomicAdd(&agg2[3 * dv + 2], z2[3 * sv + 2]);
    }
}
__global__ void k_out(const float* __restrict__ agg2, const float* __restrict__ deg,
                      const float* __restrict__ b2, float* __restrict__ out, int N) {
    int i = blockIdx.x * blockDim.x + threadIdx.x;
    if (i >= N) return;
    float dgv = deg[i];
    float di = dgv > 0.0f ? 1.0f / dgv : 0.0f;
    out[3 * i + 0] = agg2[3 * i + 0] * di + b2[0];
    out[3 * i + 1] = agg2[3 * i + 1] * di + b2[1];
    out[3 * i + 2] = agg2[3 * i + 2] * di + b2[2];
}

extern "C" void kernel_launch(void* const* d_in, const int* in_sizes, int n_in,
                              void* d_out, int out_size, void* d_ws, size_t ws_size,
                              hipStream_t stream) {
    const float* feat = (const float*)d_in[0];
    const float* W1   = (const float*)d_in[1];
    const float* b1   = (const float*)d_in[2];
    const float* W2   = (const float*)d_in[3];
    const float* b2   = (const float*)d_in[4];
    const int* edge_src = (const int*)d_in[5];
    const int* edge_dst = (const int*)d_in[6];
    float* out = (float*)d_out;

    int N = in_sizes[0] / 3;
    int E = in_sizes[5];

    // layout (4B words)
    size_t w_rec  = 0;
    size_t w_rec2 = w_rec + (size_t)NBUCK * CAP;
    size_t w_cnt_A = w_rec2 + (size_t)NBUCK * CAP;
    size_t w_after_recs_B = w_rec + (size_t)NBUCK * CAP;  // path B: no recs2

    const int BLK = 256;
    int node_grid = (N + BLK - 1) / BLK;

    double mean = (double)E * (double)LOCN / (double)(N > 0 ? N : 1);
    bool cap_ok = (mean + 8.0 * __builtin_sqrt(mean + 1.0) + 64.0) <= (double)CAP;
    bool dims_ok = (N <= (1 << SRCBITS)) && (N <= (NBUCK << LOCBITS));

    size_t needA = (w_cnt_A + NBUCK + 5 * (size_t)N) * 4;
    size_t needB = (w_after_recs_B + NBUCK + 5 * (size_t)N) * 4;

    if (dims_ok && cap_ok && ws_size >= needA) {
        uint32_t* recs  = (uint32_t*)d_ws + w_rec;
        uint32_t* recs2 = (uint32_t*)d_ws + w_rec2;
        uint32_t* gcnt  = (uint32_t*)d_ws + w_cnt_A;
        float* deg = (float*)d_ws + w_cnt_A + NBUCK;
        float* z1  = deg + (size_t)N;
        float* h   = z1 + 2 * (size_t)N;

        hipMemsetAsync(gcnt, 0, NBUCK * sizeof(uint32_t), stream);
        k_transform1<<<node_grid, BLK, 0, stream>>>(feat, W1, z1, N);
        k_build<<<BGRID, BBLK, 0, stream>>>(edge_src, edge_dst, gcnt, recs, E);
        k_sort<<<NBUCK, ABLK, 0, stream>>>(recs, gcnt, recs2);
        k_agg1<<<NBUCK, ABLK, 0, stream>>>(recs2, gcnt, z1, b1, deg, h, N);
        k_agg2<<<NBUCK, ABLK, 0, stream>>>(recs2, gcnt, h, W2, b2, deg, out, N);
    } else if (dims_ok && cap_ok && ws_size >= needB) {
        uint32_t* recs = (uint32_t*)d_ws + w_rec;
        uint32_t* gcnt = (uint32_t*)d_ws + w_after_recs_B;
        float* deg = (float*)d_ws + w_after_recs_B + NBUCK;
        float* z1  = deg + (size_t)N;
        float* h   = z1 + 2 * (size_t)N;

        hipMemsetAsync(gcnt, 0, NBUCK * sizeof(uint32_t), stream);
        k_transform1<<<node_grid, BLK, 0, stream>>>(feat, W1, z1, N);
        k_build<<<BGRID, BBLK, 0, stream>>>(edge_src, edge_dst, gcnt, recs, E);
        k_agg1<<<NBUCK, ABLK, 0, stream>>>(recs, gcnt, z1, b1, deg, h, N);
        k_agg2<<<NBUCK, ABLK, 0, stream>>>(recs, gcnt, h, W2, b2, deg, out, N);
    } else {
        // fallback: global-atomic path (needs 11N words)
        float* ws   = (float*)d_ws;
        float* deg  = ws;                   // N
        float* agg1 = ws + N;               // 2N
        float* agg2 = ws + 3 * (size_t)N;   // 3N
        float* z1   = ws + 6 * (size_t)N;   // 2N
        float* z2   = ws + 8 * (size_t)N;   // 3N
        hipMemsetAsync(d_ws, 0, (size_t)6 * N * sizeof(float), stream);
        int edge_grid = 2048;
        k_transform1<<<node_grid, BLK, 0, stream>>>(feat, W1, z1, N);
        k_edge1<<<edge_grid, BLK, 0, stream>>>(edge_src, edge_dst, z1, agg1, deg, E);
        k_mid<<<node_grid, BLK, 0, stream>>>(agg1, deg, b1, W2, z2, N);
        k_edge2<<<edge_grid, BLK, 0, stream>>>(edge_src, edge_dst, z2, agg2, E);
        k_out<<<node_grid, BLK, 0, stream>>>(agg2, deg, b2, out, N);
    }
}